// Round 1
// baseline (364.895 us; speedup 1.0000x reference)
//
#include <hip/hip_runtime.h>

// avg_voxelize: B=8, C=64, N=65536, r=32
// d_out = [ vox (B*C*r^3 floats) | norm_coords (B*3*N floats) ]
// d_ws  = [ counts (B*r^3 uint)  | idx (B*N int) ]

#define BB 8
#define CC 64
#define NN 65536
#define RR 32
#define R3 (RR * RR * RR)   // 32768

__global__ __launch_bounds__(256) void points_kernel(
    const float* __restrict__ coords,   // [B,3,N]
    float* __restrict__ norm_out,       // [B,3,N]
    int* __restrict__ idx_out,          // [B,N]
    unsigned int* __restrict__ cnt)     // [B,R3]
{
    int gid = blockIdx.x * 256 + threadIdx.x;   // 0 .. B*N-1
    int b = gid >> 16;                          // N = 65536
    int n = gid & (NN - 1);

    const float* cb = coords + (size_t)b * 3 * NN;
    float x = cb[n];
    float y = cb[NN + n];
    float z = cb[2 * NN + n];

    float nx = fminf(fmaxf(x * (float)RR, 0.0f), (float)(RR - 1));
    float ny = fminf(fmaxf(y * (float)RR, 0.0f), (float)(RR - 1));
    float nz = fminf(fmaxf(z * (float)RR, 0.0f), (float)(RR - 1));

    float* nb = norm_out + (size_t)b * 3 * NN;
    nb[n] = nx;
    nb[NN + n] = ny;
    nb[2 * NN + n] = nz;

    // jnp.round = round half to even = rintf (default rounding mode)
    int vx = (int)rintf(nx);
    int vy = (int)rintf(ny);
    int vz = (int)rintf(nz);
    int idx = (vx * RR + vy) * RR + vz;

    idx_out[gid] = idx;
    atomicAdd(&cnt[b * R3 + idx], 1u);
}

// One block per (b,c). Entire r^3 slice (128 KB) lives in LDS; accumulate
// with LDS atomics (random addrs ~2 lanes/bank -> free), write averaged
// slice with coalesced stores. No global atomics on the feature path.
__global__ __launch_bounds__(1024) void scatter_kernel(
    const float* __restrict__ feats,        // [B,C,N]
    const int* __restrict__ idx,            // [B,N]
    const unsigned int* __restrict__ cnt,   // [B,R3]
    float* __restrict__ out)                // [B,C,R3]
{
    __shared__ float acc[R3];               // 131072 bytes (gfx950: 160 KB LDS/CU)

    int c = blockIdx.x;
    int b = blockIdx.y;
    int t = threadIdx.x;

    for (int v = t; v < R3; v += 1024) acc[v] = 0.0f;
    __syncthreads();

    const float* f = feats + ((size_t)b * CC + c) * NN;
    const int* id = idx + (size_t)b * NN;

    // 16 iterations: 1024 threads x float4
    for (int n0 = t * 4; n0 < NN; n0 += 1024 * 4) {
        float4 fv = *(const float4*)(f + n0);
        int4 iv = *(const int4*)(id + n0);
        atomicAdd(&acc[iv.x], fv.x);
        atomicAdd(&acc[iv.y], fv.y);
        atomicAdd(&acc[iv.z], fv.z);
        atomicAdd(&acc[iv.w], fv.w);
    }
    __syncthreads();

    const unsigned int* cb = cnt + (size_t)b * R3;
    float* ob = out + ((size_t)b * CC + c) * R3;
    for (int v = t; v < R3; v += 1024) {
        float cf = (float)cb[v];
        ob[v] = acc[v] / fmaxf(cf, 1.0f);
    }
}

extern "C" void kernel_launch(void* const* d_in, const int* in_sizes, int n_in,
                              void* d_out, int out_size, void* d_ws, size_t ws_size,
                              hipStream_t stream) {
    const float* feats  = (const float*)d_in[0];   // [B,C,N]
    const float* coords = (const float*)d_in[1];   // [B,3,N]
    // d_in[2] = resolution scalar (32), hardcoded above.

    float* out_vox  = (float*)d_out;                         // B*C*R3
    float* out_norm = out_vox + (size_t)BB * CC * R3;        // B*3*N

    unsigned int* cnt = (unsigned int*)d_ws;                 // B*R3 uints (1 MB)
    int* idx = (int*)((char*)d_ws + (size_t)BB * R3 * sizeof(unsigned int)); // B*N ints (2 MB)

    // counts must be zeroed every call (ws is re-poisoned to 0xAA)
    hipMemsetAsync(d_ws, 0, (size_t)BB * R3 * sizeof(unsigned int), stream);

    points_kernel<<<(BB * NN) / 256, 256, 0, stream>>>(coords, out_norm, idx, cnt);

    scatter_kernel<<<dim3(CC, BB), 1024, 0, stream>>>(feats, idx, cnt, out_vox);
}

// Round 2
// 289.829 us; speedup vs baseline: 1.2590x; 1.2590x over previous
//
#include <hip/hip_runtime.h>
#include <hip/hip_bf16.h>

// avg_voxelize via counting sort: B=8, C=64, N=65536, r=32
// d_out = [ vox (B*C*r^3 floats) | norm_coords (B*3*N floats) ]
// d_ws  = [ cnt (B*R3 u32) | off (B*(R3+1) u32) | packed (B*N u32) | pos (B*N u32) ]
//
// Pipeline (no atomics on the feature path):
//  1. points_kernel : norm_coords out; idx+rank packed (ONE global atomic per point)
//  2. scan_kernel   : per-batch exclusive prefix sum of cnt -> off
//  3. pos_kernel    : pos[n] = off[idx] + rank  (sorted position per point)
//  4. gather_kernel : per (b,c): stage permuted row in LDS as bf16 (plain
//     ds_write, no atomics), segmented-sum contiguous runs, coalesced store.

#define BB 8
#define CC 64
#define NN 65536
#define RR 32
#define R3 (RR * RR * RR)          // 32768
#define OFFSTRIDE (R3 + 1)         // 32769

__global__ __launch_bounds__(256) void points_kernel(
    const float* __restrict__ coords,     // [B,3,N]
    float* __restrict__ norm_out,         // [B,3,N]
    unsigned int* __restrict__ cnt,       // [B,R3], pre-zeroed
    unsigned int* __restrict__ packed)    // [B,N]: (idx<<17)|rank
{
    int gid = blockIdx.x * 256 + threadIdx.x;   // 0 .. B*N-1
    int b = gid >> 16;
    int n = gid & (NN - 1);

    const float* cb = coords + (size_t)b * 3 * NN;
    float x = cb[n];
    float y = cb[NN + n];
    float z = cb[2 * NN + n];

    float nx = fminf(fmaxf(x * (float)RR, 0.0f), (float)(RR - 1));
    float ny = fminf(fmaxf(y * (float)RR, 0.0f), (float)(RR - 1));
    float nz = fminf(fmaxf(z * (float)RR, 0.0f), (float)(RR - 1));

    float* nb = norm_out + (size_t)b * 3 * NN;
    nb[n] = nx;
    nb[NN + n] = ny;
    nb[2 * NN + n] = nz;

    // jnp.round = round half to even = rintf
    int vx = (int)rintf(nx);
    int vy = (int)rintf(ny);
    int vz = (int)rintf(nz);
    unsigned int idx = (unsigned int)((vx * RR + vy) * RR + vz);

    unsigned int rank = atomicAdd(&cnt[b * R3 + idx], 1u);   // rank < 2^17
    packed[gid] = (idx << 17) | rank;
}

// One block per batch: exclusive prefix sum of cnt[R3] -> off[R3+1]
__global__ __launch_bounds__(1024) void scan_kernel(
    const unsigned int* __restrict__ cnt,
    unsigned int* __restrict__ off)
{
    int b = blockIdx.x;
    int t = threadIdx.x;
    const unsigned int* c = cnt + (size_t)b * R3;
    unsigned int* o = off + (size_t)b * OFFSTRIDE;

    unsigned int loc[32];
    unsigned int s = 0;
    #pragma unroll
    for (int k = 0; k < 32; k++) { loc[k] = c[t * 32 + k]; s += loc[k]; }

    __shared__ unsigned int aux[1024];
    aux[t] = s;
    __syncthreads();
    // Hillis-Steele inclusive scan over 1024 partials
    for (int d = 1; d < 1024; d <<= 1) {
        unsigned int v = (t >= d) ? aux[t - d] : 0u;
        __syncthreads();
        aux[t] += v;
        __syncthreads();
    }
    unsigned int run = (t == 0) ? 0u : aux[t - 1];
    #pragma unroll
    for (int k = 0; k < 32; k++) { o[t * 32 + k] = run; run += loc[k]; }
    if (t == 1023) o[R3] = run;   // == NN
}

__global__ __launch_bounds__(256) void pos_kernel(
    const unsigned int* __restrict__ packed,
    const unsigned int* __restrict__ off,
    unsigned int* __restrict__ pos)
{
    int gid = blockIdx.x * 256 + threadIdx.x;
    int b = gid >> 16;
    unsigned int pk = packed[gid];
    unsigned int ix = pk >> 17;
    unsigned int rk = pk & 0x1FFFFu;
    pos[gid] = off[(size_t)b * OFFSTRIDE + ix] + rk;
}

// One block per (b,c). Stage the permuted feature row in LDS as bf16
// (131072 B), then segmented-sum contiguous runs. Zero atomics.
__global__ __launch_bounds__(1024) void gather_kernel(
    const float* __restrict__ feats,        // [B,C,N]
    const unsigned int* __restrict__ pos,   // [B,N]
    const unsigned int* __restrict__ off,   // [B,R3+1]
    float* __restrict__ out)                // [B,C,R3]
{
    __shared__ __hip_bfloat16 srt[NN];      // 128 KB

    int c = blockIdx.x;
    int b = blockIdx.y;
    int t = threadIdx.x;

    const float* f = feats + ((size_t)b * CC + c) * NN;
    const unsigned int* P = pos + (size_t)b * NN;

    // 16 iterations: 1024 threads x (float4 + uint4); random LDS b16 writes
    for (int n0 = t * 4; n0 < NN; n0 += 1024 * 4) {
        float4 fv = *(const float4*)(f + n0);
        uint4 pv = *(const uint4*)(P + n0);
        srt[pv.x] = __float2bfloat16(fv.x);
        srt[pv.y] = __float2bfloat16(fv.y);
        srt[pv.z] = __float2bfloat16(fv.z);
        srt[pv.w] = __float2bfloat16(fv.w);
    }
    __syncthreads();

    const unsigned int* O = off + (size_t)b * OFFSTRIDE;
    float* ob = out + ((size_t)b * CC + c) * R3;
    for (int j = 0; j < 32; j++) {
        int v = t + j * 1024;
        unsigned int s0 = O[v];
        unsigned int s1 = O[v + 1];
        float s = 0.0f;
        for (unsigned int p = s0; p < s1; p++) s += __bfloat162float(srt[p]);
        float cf = (float)(s1 - s0);
        ob[v] = s / fmaxf(cf, 1.0f);
    }
}

extern "C" void kernel_launch(void* const* d_in, const int* in_sizes, int n_in,
                              void* d_out, int out_size, void* d_ws, size_t ws_size,
                              hipStream_t stream) {
    const float* feats  = (const float*)d_in[0];   // [B,C,N]
    const float* coords = (const float*)d_in[1];   // [B,3,N]
    // d_in[2] = resolution (32), hardcoded.

    float* out_vox  = (float*)d_out;                     // B*C*R3
    float* out_norm = out_vox + (size_t)BB * CC * R3;    // B*3*N

    char* ws = (char*)d_ws;
    unsigned int* cnt    = (unsigned int*)ws;                              // 1,048,576 B
    unsigned int* off    = (unsigned int*)(ws + 1048576);                  // 1,048,608 B
    unsigned int* packed = (unsigned int*)(ws + 1048576 + 1048608);        // 2,097,152 B (16B-aligned)
    unsigned int* pos    = (unsigned int*)(ws + 1048576 + 1048608 + 2097152); // 2,097,152 B

    hipMemsetAsync(cnt, 0, (size_t)BB * R3 * sizeof(unsigned int), stream);

    points_kernel<<<(BB * NN) / 256, 256, 0, stream>>>(coords, out_norm, cnt, packed);
    scan_kernel<<<BB, 1024, 0, stream>>>(cnt, off);
    pos_kernel<<<(BB * NN) / 256, 256, 0, stream>>>(packed, off, pos);
    gather_kernel<<<dim3(CC, BB), 1024, 0, stream>>>(feats, pos, off, out_vox);
}